// Round 14
// baseline (479.054 us; speedup 1.0000x reference)
//
#include <hip/hip_runtime.h>

#define D_MODEL 2048
#define NHEADS 16
#define DHEAD 128
#define TSEQ 2048
#define BATCH 4
#define MROWS (BATCH*TSEQ)   // 8192
#define NQKV (3*D_MODEL)     // 6144
#define BH (BATCH*NHEADS)    // 64

typedef __attribute__((ext_vector_type(4))) float f32x4;
typedef __attribute__((ext_vector_type(8))) __bf16 bf16x8;
typedef __attribute__((ext_vector_type(4))) unsigned int u32x4;

__device__ inline unsigned short f2bf(float f) {
  union { float f; unsigned u; } v; v.f = f;
  unsigned r = (v.u + 0x7fffu + ((v.u >> 16) & 1u)) >> 16;
  return (unsigned short)r;
}
// truncating pack (P only): bias ~0.2% rel, inside error budget; 1 op vs 4
__device__ inline unsigned short f2bf_t(float f) {
  union { float f; unsigned u; } v; v.f = f;
  return (unsigned short)(v.u >> 16);
}
__device__ inline float bf2f(unsigned short h) {
  union { unsigned u; float f; } v; v.u = ((unsigned)h) << 16; return v.f;
}

// async global->LDS, 16B per lane (dest = wave-uniform base + lane*16)
__device__ inline void gl_lds16(const unsigned short* g, unsigned short* l) {
  __builtin_amdgcn_global_load_lds(
      (const __attribute__((address_space(1))) unsigned int*)g,
      (__attribute__((address_space(3))) unsigned int*)l, 16, 0, 0);
}

#define CFENCE asm volatile("" ::: "memory")
#define BAR do { CFENCE; __builtin_amdgcn_s_barrier(); CFENCE; } while (0)
#define VM(n) asm volatile("s_waitcnt vmcnt(" #n ")" ::: "memory")
#define LGKM0 asm volatile("s_waitcnt lgkmcnt(0)" ::: "memory")

// ---------------- fp32 -> bf16 convert (vectorized, G13) ----------------
__global__ __launch_bounds__(256) void cvt_bf16(const float* __restrict__ in,
                                                unsigned short* __restrict__ out, int n) {
  int i = (blockIdx.x * 256 + threadIdx.x) * 8;
  if (i >= n) return;
  float4 a = *(const float4*)(in + i);
  float4 b = *(const float4*)(in + i + 4);
  union { unsigned short s[8]; u32x4 v; } r;
  r.s[0] = f2bf(a.x); r.s[1] = f2bf(a.y); r.s[2] = f2bf(a.z); r.s[3] = f2bf(a.w);
  r.s[4] = f2bf(b.x); r.s[5] = f2bf(b.y); r.s[6] = f2bf(b.z); r.s[7] = f2bf(b.w);
  *(u32x4*)(out + i) = r.v;
}

// ---------------- w [K][N] fp32 -> wT [N][K] bf16 ----------------
__global__ __launch_bounds__(256) void transw(const float* __restrict__ w,
                                              unsigned short* __restrict__ wt, int K, int N) {
  __shared__ float tile[32][33];
  int n0 = blockIdx.x * 32, k0 = blockIdx.y * 32;
  int x = threadIdx.x & 31, y = threadIdx.x >> 5;
  #pragma unroll
  for (int j = 0; j < 4; ++j)
    tile[y + j * 8][x] = w[(size_t)(k0 + y + j * 8) * N + n0 + x];
  __syncthreads();
  #pragma unroll
  for (int j = 0; j < 4; ++j)
    wt[(size_t)(n0 + y + j * 8) * K + k0 + x] = f2bf(tile[x][y + j * 8]);
}

// ---------------- RoPE cos/sin table: tab[t][f], f in [0,64) ----------------
__global__ void rope_table(float2* __restrict__ tab) {
  int t = blockIdx.x, f = threadIdx.x;
  float inv = __expf(-0.14391156831212787f * (float)f); // ln(10000)/64
  float ang = (float)t * inv;
  tab[t * 64 + f] = make_float2(cosf(ang), sinf(ang));
}

// ---------------- MFMA helpers for the 256^2 GEMM ----------------
template<int MH, int NH>
__device__ inline void mmaq(f32x4 (&acc)[8][4], const bf16x8 (&av)[4][2], const bf16x8 (&bv)[2][2]) {
  #pragma unroll
  for (int m = 0; m < 4; ++m)
    #pragma unroll
    for (int n = 0; n < 2; ++n)
      #pragma unroll
      for (int kk = 0; kk < 2; ++kk)
        acc[MH * 4 + m][NH * 2 + n] =
            __builtin_amdgcn_mfma_f32_16x16x32_bf16(av[m][kk], bv[n][kk],
                                                    acc[MH * 4 + m][NH * 2 + n], 0, 0, 0);
}

__device__ inline void rdhalf(bf16x8 (&dst)[4][2], const unsigned short* base,
                              int rbase, int l15, int l16) {
  // swizzled read: c16' = (kk*4 + l16) ^ (l15&7) -> measured conflict-free
  #pragma unroll
  for (int m = 0; m < 4; ++m)
    #pragma unroll
    for (int kk = 0; kk < 2; ++kk)
      dst[m][kk] = *(const bf16x8*)&base[(rbase + m * 16 + l15) * 64 +
                                         ((((kk << 2) | l16) ^ (l15 & 7)) << 3)];
}

__device__ inline void rdhalf2(bf16x8 (&dst)[2][2], const unsigned short* base,
                               int rbase, int l15, int l16) {
  #pragma unroll
  for (int n = 0; n < 2; ++n)
    #pragma unroll
    for (int kk = 0; kk < 2; ++kk)
      dst[n][kk] = *(const bf16x8*)&base[(rbase + n * 16 + l15) * 64 +
                                         ((((kk << 2) | l16) ^ (l15 & 7)) << 3)];
}

// ---------------- GEMM: C[M][N] = A[M][K] @ Bt[N][K]^T + bias ----------------
// Measured-best schedule (250us, MfmaUtil 35.6, conflicts 0), unchanged.
// MODE 0 epilogue (both via one LDS exchange, swizzle col^((row>>1)&31)):
//  - Q/K blocks: fused RoPE; own value from acc (no LDS re-read), only the
//    (dh^64) partner comes from LDS.
//  - V blocks: LDS transpose -> coalesced u32 writes to VT[dh][t]
//    (64 lanes x 2 packed t = 256B/instr; kills the 2B-scatter write
//    amplification seen in round 13's WRITE_SIZE).
template<int MODE>
__global__ __launch_bounds__(512, 2) void gemm_bt(
    const unsigned short* __restrict__ A,
    const unsigned short* __restrict__ Bt,
    const float* __restrict__ bias,
    int M, int N, int K,
    unsigned short* __restrict__ Qb,
    unsigned short* __restrict__ Kb,
    unsigned short* __restrict__ VTb,
    float* __restrict__ outF,
    const float2* __restrict__ tab)
{
  __shared__ unsigned short LDSU[2][2][2][128 * 64];   // [ab][parity][half]
  int tid = threadIdx.x;
  int wid = tid >> 6, lane = tid & 63;
  int wm = wid >> 2, wn = wid & 3;
  int l15 = lane & 15, l16 = lane >> 4;
  int row0 = blockIdx.y * 256, col0 = blockIdx.x * 256;

  const unsigned short* Ab = A + (size_t)row0 * K;
  const unsigned short* Bb = Bt + (size_t)col0 * K;
  int r8 = tid >> 3;                         // 0..63 staging row
  int koff = (((tid & 7) ^ (r8 & 7)) << 3);  // pre-swizzled k offset (elems)

#define STAGE_A(par, h, tc) do { \
    const unsigned short* g_ = Ab + (size_t)((h) * 128 + r8) * K + (tc) + koff; \
    gl_lds16(g_, &LDSU[0][par][h][tid * 8]); \
    gl_lds16(g_ + (size_t)64 * K, &LDSU[0][par][h][(512 + tid) * 8]); } while (0)
#define STAGE_B(par, h, tc) do { \
    const unsigned short* g_ = Bb + (size_t)((h) * 128 + r8) * K + (tc) + koff; \
    gl_lds16(g_, &LDSU[1][par][h][tid * 8]); \
    gl_lds16(g_ + (size_t)64 * K, &LDSU[1][par][h][(512 + tid) * 8]); } while (0)

  f32x4 acc[8][4] = {};
  bf16x8 a0[4][2], a1[4][2], b0[2][2], b1[2][2];
  int NT = K >> 6;

  // prologue: stage K-tile 0 (A0,B0,A1,B1); force A0,B0 landed, cross-wave
  STAGE_A(0, 0, 0); STAGE_B(0, 0, 0); STAGE_A(0, 1, 0); STAGE_B(0, 1, 0);
  VM(4); BAR;

  for (int kt = 0; kt < NT - 1; ++kt) {
    int par = kt & 1, parn = par ^ 1;
    int kn = (kt + 1) << 6;
    // ---- q0 ----
    rdhalf(a0, &LDSU[0][par][0][0], wm * 64, l15, l16);
    rdhalf2(b0, &LDSU[1][par][0][0], wn * 32, l15, l16);
    STAGE_A(parn, 0, kn); STAGE_B(parn, 0, kn);
    VM(6); BAR; LGKM0;                 // forces A1(kt), window 3 phases
    __builtin_amdgcn_s_setprio(1);
    mmaq<0, 0>(acc, a0, b0);
    __builtin_amdgcn_s_setprio(0);
    // ---- q1 ----
    rdhalf(a1, &LDSU[0][par][1][0], wm * 64, l15, l16);
    STAGE_A(parn, 1, kn);
    VM(6); BAR; LGKM0;                 // forces B1(kt), window 3 phases
    __builtin_amdgcn_s_setprio(1);
    mmaq<1, 0>(acc, a1, b0);
    __builtin_amdgcn_s_setprio(0);
    // ---- q2 (no barrier: b1 already forced at q1's VM+BAR) ----
    rdhalf2(b1, &LDSU[1][par][1][0], wn * 32, l15, l16);
    STAGE_B(parn, 1, kn);
    __builtin_amdgcn_s_setprio(1);
    mmaq<0, 1>(acc, a0, b1);
    __builtin_amdgcn_s_setprio(0);
    // ---- q3 ----
    VM(4); BAR;                        // forces A0',B0'(kt+1), window 3 phases
    __builtin_amdgcn_s_setprio(1);
    mmaq<1, 1>(acc, a1, b1);
    __builtin_amdgcn_s_setprio(0);
  }

  // ---- final K-tile (no staging; in flight: A1,B1 of this tile = 4 loads) ----
  {
    int par = (NT - 1) & 1;
    rdhalf(a0, &LDSU[0][par][0][0], wm * 64, l15, l16);
    rdhalf2(b0, &LDSU[1][par][0][0], wn * 32, l15, l16);
    VM(2); BAR; LGKM0;                 // forces A1
    __builtin_amdgcn_s_setprio(1);
    mmaq<0, 0>(acc, a0, b0);
    __builtin_amdgcn_s_setprio(0);
    rdhalf(a1, &LDSU[0][par][1][0], wm * 64, l15, l16);
    VM(0); BAR;                        // forces B1
    rdhalf2(b1, &LDSU[1][par][1][0], wn * 32, l15, l16);
    __builtin_amdgcn_s_setprio(1);
    mmaq<1, 0>(acc, a1, b0);
    mmaq<0, 1>(acc, a0, b1);
    mmaq<1, 1>(acc, a1, b1);
    __builtin_amdgcn_s_setprio(0);
  }

  // ---- epilogue ----
  if (MODE == 0) {
    int blkq = col0 >> 8;                       // 0..7 Q, 8..15 K, 16..23 V
    const float SCQ = 0.08838834764831845f * 1.4426950408889634f; // 1/sqrt(128)*log2e
    float* Lf = (float*)&LDSU[0][0][0][0];      // 128 x 256 f32 = 128KB
    BAR;                                        // all waves done reading LDS
    #pragma unroll
    for (int c = 0; c < 2; ++c) {
      // store chunk c (rows c*128..c*128+127) biased to LDS, swizzled
      #pragma unroll
      for (int m = 0; m < 4; ++m) {
        #pragma unroll
        for (int an = 0; an < 4; ++an) {
          int nh = an >> 1, n = an & 1;
          int col_l = nh * 128 + wn * 32 + n * 16 + l15;
          float bs = bias[col0 + col_l];
          #pragma unroll
          for (int r = 0; r < 4; ++r) {
            int row_l = wm * 64 + m * 16 + l16 * 4 + r;
            Lf[row_l * 256 + (col_l ^ ((row_l >> 1) & 31))] = acc[c * 4 + m][an][r] + bs;
          }
        }
      }
      BAR;
      if (blkq < 16) {
        // Q/K: fused RoPE; v1 from acc, v2 (partner dh^64) from LDS
        bool isQ = blkq < 8;
        #pragma unroll
        for (int m = 0; m < 4; ++m) {
          #pragma unroll
          for (int an = 0; an < 4; ++an) {
            int nh = an >> 1, n = an & 1;
            int col_l = nh * 128 + wn * 32 + n * 16 + l15;
            int col = col0 + col_l;
            int rem = col & 2047;
            int h = rem >> 7, dh = rem & 127;
            float bs = bias[col];
            #pragma unroll
            for (int r = 0; r < 4; ++r) {
              int row_l = wm * 64 + m * 16 + l16 * 4 + r;
              float v1 = acc[c * 4 + m][an][r] + bs;
              float v2 = Lf[row_l * 256 + ((col_l ^ 64) ^ ((row_l >> 1) & 31))];
              int row = row0 + c * 128 + row_l;
              int t = row & 2047;
              float2 cs = tab[t * 64 + (dh & 63)];
              float o = (dh & 64) ? (v1 * cs.x + v2 * cs.y)
                                  : (v1 * cs.x - v2 * cs.y);
              if (isQ) o *= SCQ;
              int b = row >> 11;
              int bh = b * NHEADS + h;
              (isQ ? Qb : Kb)[((size_t)bh * TSEQ + t) * DHEAD + dh] = f2bf(o);
            }
          }
        }
      } else {
        // V: LDS transpose -> coalesced u32 writes to VT[dh][t]
        int t0g = row0 + c * 128;
        int b = t0g >> 11;
        int t0 = t0g & 2047;
        int xr = lane & 31;                     // (2*lane)>>1 & 31
        #pragma unroll
        for (int i = 0; i < 32; ++i) {
          int dc = wid * 32 + i;
          int col = col0 + dc;
          int rem = col & 2047;
          int h = rem >> 7, dh = rem & 127;
          int bh = b * NHEADS + h;
          int idx = (2 * lane) * 256 + (dc ^ xr);
          float lo = Lf[idx];
          float hi = Lf[idx + 256];
          unsigned u = ((unsigned)f2bf(hi) << 16) | (unsigned)f2bf(lo);
          *(unsigned*)&VTb[((size_t)bh * DHEAD + dh) * TSEQ + t0 + 2 * lane] = u;
        }
      }
      BAR;                                      // protect LDS before chunk 2
    }
  } else {
    #pragma unroll
    for (int am = 0; am < 8; ++am) {
      int mh = am >> 2, m = am & 3;
      #pragma unroll
      for (int an = 0; an < 4; ++an) {
        int nh = an >> 1, n = an & 1;
        int col = col0 + nh * 128 + wn * 32 + n * 16 + l15;
        float bs = bias[col];
        #pragma unroll
        for (int r = 0; r < 4; ++r) {
          int row = row0 + mh * 128 + wm * 64 + m * 16 + l16 * 4 + r;  // verified C layout
          outF[(size_t)row * N + col] = acc[am][an][r] + bs;
        }
      }
    }
  }
#undef STAGE_A
#undef STAGE_B
}

// ---------------- causal flash attention: paired q-tiles, LDS dbuf K/V ----------------
// (unchanged from round 12: ballot-before-reduce, deferred l-reduction,
// truncating P pack, mask-skip, defer-max)
__global__ __launch_bounds__(256, 2) void attn_fwd(
    const unsigned short* __restrict__ Qb,
    const unsigned short* __restrict__ Kb,
    const unsigned short* __restrict__ VTb,
    unsigned short* __restrict__ ctx)
{
  __shared__ unsigned short Ksm[2][64 * 128];   // [kv][d], swizzled
  __shared__ unsigned short Vsm[2][128 * 64];   // [d][kv], swizzled
  __shared__ unsigned short Psm[4][32 * 64];    // per-wave P, swizzled
  int bid = blockIdx.x;
  int bh = bid & 63, pr = bid >> 6;
  int hi = 15 - pr, lo = pr;
  int tid = threadIdx.x, wid = tid >> 6, lane = tid & 63;
  int l15 = lane & 15, l16 = lane >> 4;
  const unsigned short* Kh = Kb + (size_t)bh * TSEQ * DHEAD;
  const unsigned short* Vh = VTb + (size_t)bh * DHEAD * TSEQ;
  unsigned short* P = &Psm[wid][0];
  int swzl = (l15 & 7) << 4;

  int krow = tid >> 4;
  int kcol = (((tid & 15) << 4) ^ ((krow & 7) << 4)) >> 1;
  int vrow = tid >> 3;
  int vcol = (((tid & 7) << 4) ^ ((vrow & 7) << 4)) >> 1;
  int ldsl = tid * 8;

  int ck[4];
  #pragma unroll
  for (int kk = 0; kk < 4; ++kk) ck[kk] = ((kk * 64 + l16 * 16) ^ swzl) >> 1;

  bf16x8 qf[2][4];
  f32x4 accO[2][8];
  float mrow[2][4], lrow[2][4];   // lrow = PER-LANE partial row sum

  int qbase = hi * 128 + wid * 32;
  #pragma unroll
  for (int m = 0; m < 2; ++m) {
    #pragma unroll
    for (int n = 0; n < 8; ++n) accO[m][n] = (f32x4)0.f;
    #pragma unroll
    for (int r = 0; r < 4; ++r) { mrow[m][r] = -1e30f; lrow[m][r] = 0.f; }
    #pragma unroll
    for (int kk = 0; kk < 4; ++kk)
      qf[m][kk] = *(const bf16x8*)&Qb[((size_t)bh * TSEQ + qbase + m * 16 + l15) * DHEAD
                                      + kk * 32 + l16 * 8];
  }

  int nt0 = 2 * hi + 2;
  int ntt = nt0 + 2 * lo + 2;

  {
    const unsigned short* kg = Kh + krow * DHEAD + kcol;
    const unsigned short* vg = Vh + (size_t)vrow * TSEQ + vcol;
    #pragma unroll
    for (int ps = 0; ps < 4; ++ps) {
      gl_lds16(kg + ps * 16 * DHEAD, &Ksm[0][ldsl + ps * 2048]);
      gl_lds16(vg + (size_t)ps * 32 * TSEQ, &Vsm[0][ldsl + ps * 2048]);
    }
  }
  __syncthreads();

  for (int it = 0; it < ntt; ++it) {
    int buf = it & 1;
    int kv0 = ((it >= nt0) ? (it - nt0) : it) * 64;

    if (it + 1 < ntt) {
      int n2 = it + 1;
      int kv2 = ((n2 >= nt0) ? (n2 - nt0) : n2) * 64;
      const unsigned short* kg = Kh + (size_t)(kv2 + krow) * DHEAD + kcol;
      const unsigned short* vg = Vh + (size_t)vrow * TSEQ + kv2 + vcol;
      #pragma unroll
      for (int ps = 0; ps < 4; ++ps) {
        gl_lds16(kg + ps * 16 * DHEAD, &Ksm[buf ^ 1][ldsl + ps * 2048]);
        gl_lds16(vg + (size_t)ps * 32 * TSEQ, &Vsm[buf ^ 1][ldsl + ps * 2048]);
      }
    }

    if (kv0 <= qbase + 31) {
      const unsigned short* Kt = Ksm[buf];
      const unsigned short* Vt = Vsm[buf];

      f32x4 S[2][4] = {};
      #pragma unroll
      for (int n = 0; n < 4; ++n) {
        bf16x8 kf[4];
        #pragma unroll
        for (int kk = 0; kk < 4; ++kk)
          kf[kk] = *(const bf16x8*)&Kt[(n * 16 + l15) * DHEAD + ck[kk]];
        #pragma unroll
        for (int m = 0; m < 2; ++m)
          #pragma unroll
          for (int kk = 0; kk < 4; ++kk)
            S[m][n] = __builtin_amdgcn_mfma_f32_16x16x32_bf16(qf[m][kk], kf[kk], S[m][n], 0, 0, 0);
      }

      // ---- pass 1: mask (diagonal tile only) + per-lane LOCAL max ----
      bool masked = (kv0 + 63 > qbase);    // wave-uniform
      float lmax[2][4];
      float grow = -1e30f;
      #pragma unroll
      for (int m = 0; m < 2; ++m) {
        #pragma unroll
        for (int r = 0; r < 4; ++r) {
          if (masked) {
            int qg = qbase + m * 16 + l16 * 4 + r;
            if (kv0 + l15      > qg) S[m][0][r] = -1e30f;
            if (kv0 + 16 + l15 > qg) S[m][1][r] = -1e30f;
            if (kv0 + 32 + l15 > qg) S[m][2][r] = -1e30f;
            if (kv0 + 48 + l15 > qg) S[m][3][r] = -1e30f;
          }
          float v = fmaxf(fmaxf(S[m][0][r], S[m][1][r]), fmaxf(S[m][2][r], S[m][3][r]));
          lmax[m][r] = v;
          grow = fmaxf(grow, v - mrow[m][r]);
        }
      }

      // ---- defer-max: full reduce + rescale only when some LANE grew >8 ----
      if (__any(grow > 8.f)) {
        #pragma unroll
        for (int m = 0; m < 2; ++m)
          #pragma unroll
          for (int r = 0; r < 4; ++r) {
            float v = lmax[m][r];
            #pragma unroll
            for (int off = 1; off < 16; off <<= 1) v = fmaxf(v, __shfl_xor(v, off));
            float mnew = fmaxf(mrow[m][r], v);
            float alpha = exp2f(mrow[m][r] - mnew);
            mrow[m][r] = mnew;
            lrow[m][r] *= alpha;
            #pragma unroll
            for (int n = 0; n < 8; ++n) accO[m][n][r] *= alpha;
          }
      }

      // ---- pass 2: P = exp2(S - m), per-lane partial sums, P writes ----
      #pragma unroll
      for (int m = 0; m < 2; ++m) {
        #pragma unroll
        for (int r = 0; r < 4; ++r) {
          float mr = mrow[m][r];
          float p0 = exp2f(S[m][0][r] - mr), p1 = exp2f(S[m][1][r] - mr);
          float p2 = exp2f(S[m][2][r] - mr), p3 = exp2f(S[m][3][r] - mr);
          lrow[m][r] += (p0 + p1) + (p2 + p3);   // partial; reduced at flush
          int qr = m * 16 + l16 * 4 + r;
          int ws = (qr & 7) << 4;
          P[qr * 64 + ((((l15 << 1))      ^ ws) >> 1)] = f2bf_t(p0);
          P[qr * 64 + (((32 + (l15 << 1)) ^ ws) >> 1)] = f2bf_t(p1);
          P[qr * 64 + (((64 + (l15 << 1)) ^ ws) >> 1)] = f2bf_t(p2);
          P[qr * 64 + (((96 + (l15 << 1)) ^ ws) >> 1)] = f2bf_t(p3);
        }
      }

      bf16x8 pf[2][2];
      #pragma unroll
      for (int m = 0; m < 2; ++m)
        #pragma unroll
        for (int kk = 0; kk < 2; ++kk)
          pf[m][kk] = *(const bf16x8*)&P[(m * 16 + l15) * 64 + ck[kk]];
      #pragma unroll
      for (int n = 0; n < 8; ++n) {
        bf16x8 vf[2];
        #pragma unroll
        for (int kk = 0; kk < 2; ++kk)
          vf[kk] = *(const bf16x8*)&Vt[(n * 16 + l15) * 64 + ck[kk]];
        #pragma unroll
        for (int m = 0; m < 2; ++m)
          #pragma unroll
          for (int kk = 0; kk < 2; ++kk)
            accO[m][n] = __builtin_amdgcn_mfma_f32_16x16x32_bf16(pf[m][kk], vf[kk], accO[m][n], 0, 0, 0);
      }
    }

    if (it == nt0 - 1) {
      int b = bh >> 4, h = bh & 15;
      #pragma unroll
      for (int m = 0; m < 2; ++m)
        #pragma unroll
        for (int r = 0; r < 4; ++r) {
          float ls = lrow[m][r];
          #pragma unroll
          for (int off = 1; off < 16; off <<= 1) ls += __shfl_xor(ls, off);
          float inv = 1.0f / ls;
          int t = qbase + m * 16 + l16 * 4 + r;
          size_t base = ((size_t)b * TSEQ + t) * D_MODEL + h * DHEAD;
          #pragma unroll
          for (int n = 0; n < 8; ++n)
            ctx[base + n * 16 + l15] = f2bf(accO[m][n][r] * inv);
        }
      qbase = lo * 128 + wid * 32;
      #pragma unroll
      for (int m = 0; m < 2; ++m) {
        #pragma unroll
        for (int n = 0; n < 8; ++n) accO[m][n] = (f32x4)0.f;
        #pragma unroll
        for (int r = 0; r < 4; ++r) { mrow[m][r] = -1e30f; lrow[m][r] = 0.f; }
        #pragma unroll
        for (int kk = 0; kk < 4; ++kk)
          qf[m][kk] = *(const bf16x8*)&Qb[((size_t)bh * TSEQ + qbase + m * 16 + l15) * DHEAD
                                          + kk * 32 + l16 * 8];
      }
    }

    __syncthreads();
  }

  {
    int b = bh >> 4, h = bh & 15;
    #pragma unroll
    for (int m = 0; m < 2; ++m)
      #pragma unroll
      for (int r = 0; r < 4; ++r) {
        float ls = lrow[m][r];
        #pragma unroll
        for (int off = 1; off < 16; off <<= 1) ls += __shfl_xor(ls, off);
        float inv = 1.0f / ls;
        int t = qbase + m * 16 + l16 * 4 + r;
        size_t base = ((size_t)b * TSEQ + t) * D_MODEL + h * DHEAD;
        #pragma unroll
        for (int n = 0; n < 8; ++n)
          ctx[base + n * 16 + l15] = f2bf(accO[m][n][r] * inv);
      }
  }
}

extern "C" void kernel_launch(void* const* d_in, const int* in_sizes, int n_in,
                              void* d_out, int out_size, void* d_ws, size_t ws_size,
                              hipStream_t stream)
{
  const float* x     = (const float*)d_in[0];
  const float* w_qkv = (const float*)d_in[1];
  const float* b_qkv = (const float*)d_in[2];
  const float* w_out = (const float*)d_in[3];
  const float* b_out = (const float*)d_in[4];
  float* out = (float*)d_out;

  unsigned short* xb    = (unsigned short*)d_ws;               // [8192][2048]; reused as ctx
  unsigned short* wqkvT = xb    + (size_t)MROWS * D_MODEL;     // [6144][2048]
  unsigned short* woutT = wqkvT + (size_t)NQKV * D_MODEL;      // [2048][2048]
  unsigned short* Qb    = woutT + (size_t)D_MODEL * D_MODEL;   // [64][2048][128]
  unsigned short* Kb    = Qb    + (size_t)BH * TSEQ * DHEAD;
  unsigned short* VTb   = Kb    + (size_t)BH * TSEQ * DHEAD;   // [64][128][2048]
  float2* tab = (float2*)(VTb + (size_t)BH * TSEQ * DHEAD);    // [2048][64]

  cvt_bf16<<<MROWS * D_MODEL / 2048, 256, 0, stream>>>(x, xb, MROWS * D_MODEL);
  transw<<<dim3(NQKV / 32, D_MODEL / 32), 256, 0, stream>>>(w_qkv, wqkvT, D_MODEL, NQKV);
  transw<<<dim3(D_MODEL / 32, D_MODEL / 32), 256, 0, stream>>>(w_out, woutT, D_MODEL, D_MODEL);
  rope_table<<<TSEQ, 64, 0, stream>>>(tab);
  gemm_bt<0><<<dim3(NQKV / 256, MROWS / 256), 512, 0, stream>>>(
      xb, wqkvT, b_qkv, MROWS, NQKV, D_MODEL, Qb, Kb, VTb, nullptr, tab);
  attn_fwd<<<dim3(512), 256, 0, stream>>>(Qb, Kb, VTb, xb);
  gemm_bt<1><<<dim3(D_MODEL / 256, MROWS / 256), 512, 0, stream>>>(
      xb, woutT, b_out, MROWS, D_MODEL, D_MODEL, nullptr, nullptr, nullptr, out, nullptr);
}

// Round 15
// 423.347 us; speedup vs baseline: 1.1316x; 1.1316x over previous
//
#include <hip/hip_runtime.h>

#define D_MODEL 2048
#define NHEADS 16
#define DHEAD 128
#define TSEQ 2048
#define BATCH 4
#define MROWS (BATCH*TSEQ)   // 8192
#define NQKV (3*D_MODEL)     // 6144
#define BH (BATCH*NHEADS)    // 64

typedef __attribute__((ext_vector_type(4))) float f32x4;
typedef __attribute__((ext_vector_type(8))) __bf16 bf16x8;
typedef __attribute__((ext_vector_type(4))) unsigned int u32x4;

__device__ inline unsigned short f2bf(float f) {
  union { float f; unsigned u; } v; v.f = f;
  unsigned r = (v.u + 0x7fffu + ((v.u >> 16) & 1u)) >> 16;
  return (unsigned short)r;
}
// truncating pack (P only): bias ~0.2% rel, inside error budget; 1 op vs 4
__device__ inline unsigned short f2bf_t(float f) {
  union { float f; unsigned u; } v; v.f = f;
  return (unsigned short)(v.u >> 16);
}
__device__ inline float bf2f(unsigned short h) {
  union { unsigned u; float f; } v; v.u = ((unsigned)h) << 16; return v.f;
}

// async global->LDS, 16B per lane (dest = wave-uniform base + lane*16)
__device__ inline void gl_lds16(const unsigned short* g, unsigned short* l) {
  __builtin_amdgcn_global_load_lds(
      (const __attribute__((address_space(1))) unsigned int*)g,
      (__attribute__((address_space(3))) unsigned int*)l, 16, 0, 0);
}

#define CFENCE asm volatile("" ::: "memory")
#define BAR do { CFENCE; __builtin_amdgcn_s_barrier(); CFENCE; } while (0)
#define VM(n) asm volatile("s_waitcnt vmcnt(" #n ")" ::: "memory")
#define LGKM0 asm volatile("s_waitcnt lgkmcnt(0)" ::: "memory")

// ---------------- fp32 -> bf16 convert (vectorized, G13) ----------------
__global__ __launch_bounds__(256) void cvt_bf16(const float* __restrict__ in,
                                                unsigned short* __restrict__ out, int n) {
  int i = (blockIdx.x * 256 + threadIdx.x) * 8;
  if (i >= n) return;
  float4 a = *(const float4*)(in + i);
  float4 b = *(const float4*)(in + i + 4);
  union { unsigned short s[8]; u32x4 v; } r;
  r.s[0] = f2bf(a.x); r.s[1] = f2bf(a.y); r.s[2] = f2bf(a.z); r.s[3] = f2bf(a.w);
  r.s[4] = f2bf(b.x); r.s[5] = f2bf(b.y); r.s[6] = f2bf(b.z); r.s[7] = f2bf(b.w);
  *(u32x4*)(out + i) = r.v;
}

// ---------------- w [K][N] fp32 -> wT [N][K] bf16 ----------------
__global__ __launch_bounds__(256) void transw(const float* __restrict__ w,
                                              unsigned short* __restrict__ wt, int K, int N) {
  __shared__ float tile[32][33];
  int n0 = blockIdx.x * 32, k0 = blockIdx.y * 32;
  int x = threadIdx.x & 31, y = threadIdx.x >> 5;
  #pragma unroll
  for (int j = 0; j < 4; ++j)
    tile[y + j * 8][x] = w[(size_t)(k0 + y + j * 8) * N + n0 + x];
  __syncthreads();
  #pragma unroll
  for (int j = 0; j < 4; ++j)
    wt[(size_t)(n0 + y + j * 8) * K + k0 + x] = f2bf(tile[x][y + j * 8]);
}

// ---------------- RoPE cos/sin table: tab[t][f], f in [0,64) ----------------
__global__ void rope_table(float2* __restrict__ tab) {
  int t = blockIdx.x, f = threadIdx.x;
  float inv = __expf(-0.14391156831212787f * (float)f); // ln(10000)/64
  float ang = (float)t * inv;
  tab[t * 64 + f] = make_float2(cosf(ang), sinf(ang));
}

// ---------------- MFMA helpers for the 256^2 GEMM ----------------
template<int MH, int NH>
__device__ inline void mmaq(f32x4 (&acc)[8][4], const bf16x8 (&av)[4][2], const bf16x8 (&bv)[2][2]) {
  #pragma unroll
  for (int m = 0; m < 4; ++m)
    #pragma unroll
    for (int n = 0; n < 2; ++n)
      #pragma unroll
      for (int kk = 0; kk < 2; ++kk)
        acc[MH * 4 + m][NH * 2 + n] =
            __builtin_amdgcn_mfma_f32_16x16x32_bf16(av[m][kk], bv[n][kk],
                                                    acc[MH * 4 + m][NH * 2 + n], 0, 0, 0);
}

__device__ inline void rdhalf(bf16x8 (&dst)[4][2], const unsigned short* base,
                              int rbase, int l15, int l16) {
  // swizzled read: c16' = (kk*4 + l16) ^ (l15&7) -> measured conflict-free
  #pragma unroll
  for (int m = 0; m < 4; ++m)
    #pragma unroll
    for (int kk = 0; kk < 2; ++kk)
      dst[m][kk] = *(const bf16x8*)&base[(rbase + m * 16 + l15) * 64 +
                                         ((((kk << 2) | l16) ^ (l15 & 7)) << 3)];
}

__device__ inline void rdhalf2(bf16x8 (&dst)[2][2], const unsigned short* base,
                               int rbase, int l15, int l16) {
  #pragma unroll
  for (int n = 0; n < 2; ++n)
    #pragma unroll
    for (int kk = 0; kk < 2; ++kk)
      dst[n][kk] = *(const bf16x8*)&base[(rbase + n * 16 + l15) * 64 +
                                         ((((kk << 2) | l16) ^ (l15 & 7)) << 3)];
}

// ---------------- GEMM: C[M][N] = A[M][K] @ Bt[N][K]^T + bias ----------------
// Measured-best schedule (250us, MfmaUtil 35.6, conflicts 0), unchanged.
// MODE 0 epilogue = round-13 structure (measured 260us total-best):
//  - Q/K blocks: fused RoPE via LDS exchange; own value (v1) taken from acc
//    registers (r14's one proven win), only the (dh^64) partner from LDS.
//  - V blocks: direct 2B scatter (L2 merges the lines; r14's exchange was
//    a measured regression -- reverted).
template<int MODE>
__global__ __launch_bounds__(512, 2) void gemm_bt(
    const unsigned short* __restrict__ A,
    const unsigned short* __restrict__ Bt,
    const float* __restrict__ bias,
    int M, int N, int K,
    unsigned short* __restrict__ Qb,
    unsigned short* __restrict__ Kb,
    unsigned short* __restrict__ VTb,
    float* __restrict__ outF,
    const float2* __restrict__ tab)
{
  __shared__ unsigned short LDSU[2][2][2][128 * 64];   // [ab][parity][half]
  int tid = threadIdx.x;
  int wid = tid >> 6, lane = tid & 63;
  int wm = wid >> 2, wn = wid & 3;
  int l15 = lane & 15, l16 = lane >> 4;
  int row0 = blockIdx.y * 256, col0 = blockIdx.x * 256;

  const unsigned short* Ab = A + (size_t)row0 * K;
  const unsigned short* Bb = Bt + (size_t)col0 * K;
  int r8 = tid >> 3;                         // 0..63 staging row
  int koff = (((tid & 7) ^ (r8 & 7)) << 3);  // pre-swizzled k offset (elems)

#define STAGE_A(par, h, tc) do { \
    const unsigned short* g_ = Ab + (size_t)((h) * 128 + r8) * K + (tc) + koff; \
    gl_lds16(g_, &LDSU[0][par][h][tid * 8]); \
    gl_lds16(g_ + (size_t)64 * K, &LDSU[0][par][h][(512 + tid) * 8]); } while (0)
#define STAGE_B(par, h, tc) do { \
    const unsigned short* g_ = Bb + (size_t)((h) * 128 + r8) * K + (tc) + koff; \
    gl_lds16(g_, &LDSU[1][par][h][tid * 8]); \
    gl_lds16(g_ + (size_t)64 * K, &LDSU[1][par][h][(512 + tid) * 8]); } while (0)

  f32x4 acc[8][4] = {};
  bf16x8 a0[4][2], a1[4][2], b0[2][2], b1[2][2];
  int NT = K >> 6;

  // prologue: stage K-tile 0 (A0,B0,A1,B1); force A0,B0 landed, cross-wave
  STAGE_A(0, 0, 0); STAGE_B(0, 0, 0); STAGE_A(0, 1, 0); STAGE_B(0, 1, 0);
  VM(4); BAR;

  for (int kt = 0; kt < NT - 1; ++kt) {
    int par = kt & 1, parn = par ^ 1;
    int kn = (kt + 1) << 6;
    // ---- q0 ----
    rdhalf(a0, &LDSU[0][par][0][0], wm * 64, l15, l16);
    rdhalf2(b0, &LDSU[1][par][0][0], wn * 32, l15, l16);
    STAGE_A(parn, 0, kn); STAGE_B(parn, 0, kn);
    VM(6); BAR; LGKM0;                 // forces A1(kt), window 3 phases
    __builtin_amdgcn_s_setprio(1);
    mmaq<0, 0>(acc, a0, b0);
    __builtin_amdgcn_s_setprio(0);
    // ---- q1 ----
    rdhalf(a1, &LDSU[0][par][1][0], wm * 64, l15, l16);
    STAGE_A(parn, 1, kn);
    VM(6); BAR; LGKM0;                 // forces B1(kt), window 3 phases
    __builtin_amdgcn_s_setprio(1);
    mmaq<1, 0>(acc, a1, b0);
    __builtin_amdgcn_s_setprio(0);
    // ---- q2 (no barrier: b1 already forced at q1's VM+BAR) ----
    rdhalf2(b1, &LDSU[1][par][1][0], wn * 32, l15, l16);
    STAGE_B(parn, 1, kn);
    __builtin_amdgcn_s_setprio(1);
    mmaq<0, 1>(acc, a0, b1);
    __builtin_amdgcn_s_setprio(0);
    // ---- q3 ----
    VM(4); BAR;                        // forces A0',B0'(kt+1), window 3 phases
    __builtin_amdgcn_s_setprio(1);
    mmaq<1, 1>(acc, a1, b1);
    __builtin_amdgcn_s_setprio(0);
  }

  // ---- final K-tile (no staging; in flight: A1,B1 of this tile = 4 loads) ----
  {
    int par = (NT - 1) & 1;
    rdhalf(a0, &LDSU[0][par][0][0], wm * 64, l15, l16);
    rdhalf2(b0, &LDSU[1][par][0][0], wn * 32, l15, l16);
    VM(2); BAR; LGKM0;                 // forces A1
    __builtin_amdgcn_s_setprio(1);
    mmaq<0, 0>(acc, a0, b0);
    __builtin_amdgcn_s_setprio(0);
    rdhalf(a1, &LDSU[0][par][1][0], wm * 64, l15, l16);
    VM(0); BAR;                        // forces B1
    rdhalf2(b1, &LDSU[1][par][1][0], wn * 32, l15, l16);
    __builtin_amdgcn_s_setprio(1);
    mmaq<1, 0>(acc, a1, b0);
    mmaq<0, 1>(acc, a0, b1);
    mmaq<1, 1>(acc, a1, b1);
    __builtin_amdgcn_s_setprio(0);
  }

  // ---- epilogue ----
  if (MODE == 0 && (col0 >> 8) < 16) {
    // Q or K block: fused RoPE via LDS exchange (LDS dead after K-loop)
    const float SCQ = 0.08838834764831845f * 1.4426950408889634f; // 1/sqrt(128)*log2e
    bool isQ = (col0 >> 8) < 8;
    float* Lf = (float*)&LDSU[0][0][0][0];     // 128KB = 128 x 256 f32
    BAR;                                        // all waves done reading LDS
    #pragma unroll
    for (int c = 0; c < 2; ++c) {
      #pragma unroll
      for (int m = 0; m < 4; ++m) {
        #pragma unroll
        for (int an = 0; an < 4; ++an) {
          int nh = an >> 1, n = an & 1;
          int col_l = nh * 128 + wn * 32 + n * 16 + l15;
          float bs = bias[col0 + col_l];
          #pragma unroll
          for (int r = 0; r < 4; ++r) {
            int row_l = wm * 64 + m * 16 + l16 * 4 + r;
            int swz = ((row_l >> 2) & 3) << 3;   // 2-way-free bank rotate
            Lf[row_l * 256 + (col_l ^ swz)] = acc[c * 4 + m][an][r] + bs;
          }
        }
      }
      BAR;
      #pragma unroll
      for (int m = 0; m < 4; ++m) {
        #pragma unroll
        for (int an = 0; an < 4; ++an) {
          int nh = an >> 1, n = an & 1;
          int col_l = nh * 128 + wn * 32 + n * 16 + l15;
          int col = col0 + col_l;
          int rem = col & 2047;
          int h = rem >> 7, dh = rem & 127;
          float bs = bias[col];
          #pragma unroll
          for (int r = 0; r < 4; ++r) {
            int row_l = wm * 64 + m * 16 + l16 * 4 + r;
            int swz = ((row_l >> 2) & 3) << 3;
            float v1 = acc[c * 4 + m][an][r] + bs;            // own value from regs
            float v2 = Lf[row_l * 256 + ((col_l ^ 64) ^ swz)]; // partner from LDS
            int row = row0 + c * 128 + row_l;
            int t = row & 2047;
            float2 cs = tab[t * 64 + (dh & 63)];
            // rope: f-half: v1*c - v2*s ; (f+64)-half: v1*c + v2*s
            float o = (dh & 64) ? (v1 * cs.x + v2 * cs.y)
                                : (v1 * cs.x - v2 * cs.y);
            if (isQ) o *= SCQ;
            int b = row >> 11;
            int bh = b * NHEADS + h;
            (isQ ? Qb : Kb)[((size_t)bh * TSEQ + t) * DHEAD + dh] = f2bf(o);
          }
        }
      }
      BAR;                                      // protect LDS before chunk 2
    }
  } else {
    #pragma unroll
    for (int am = 0; am < 8; ++am) {
      int mh = am >> 2, m = am & 3;
      #pragma unroll
      for (int an = 0; an < 4; ++an) {
        int nh = an >> 1, n = an & 1;
        int col = col0 + nh * 128 + wn * 32 + n * 16 + l15;
        float bs = bias[col];
        #pragma unroll
        for (int r = 0; r < 4; ++r) {
          int row = row0 + mh * 128 + wm * 64 + m * 16 + l16 * 4 + r;  // verified C layout
          float val = acc[am][an][r] + bs;
          if (MODE == 0) {
            // V block (col >= 4096): transposed scatter (L2 merges lines)
            int rem = col & 2047;
            int h = rem >> 7, dh = rem & 127;
            int b = row >> 11, t = row & 2047;
            int bh = b * NHEADS + h;
            VTb[((size_t)bh * DHEAD + dh) * TSEQ + t] = f2bf(val);
          } else {
            outF[(size_t)row * N + col] = val;
          }
        }
      }
    }
  }
#undef STAGE_A
#undef STAGE_B
}

// ---------------- causal flash attention: paired q-tiles, LDS dbuf K/V ----------------
// (unchanged: ballot-before-reduce, deferred l-reduction, truncating P pack,
// mask-skip, defer-max)
__global__ __launch_bounds__(256, 2) void attn_fwd(
    const unsigned short* __restrict__ Qb,
    const unsigned short* __restrict__ Kb,
    const unsigned short* __restrict__ VTb,
    unsigned short* __restrict__ ctx)
{
  __shared__ unsigned short Ksm[2][64 * 128];   // [kv][d], swizzled
  __shared__ unsigned short Vsm[2][128 * 64];   // [d][kv], swizzled
  __shared__ unsigned short Psm[4][32 * 64];    // per-wave P, swizzled
  int bid = blockIdx.x;
  int bh = bid & 63, pr = bid >> 6;
  int hi = 15 - pr, lo = pr;
  int tid = threadIdx.x, wid = tid >> 6, lane = tid & 63;
  int l15 = lane & 15, l16 = lane >> 4;
  const unsigned short* Kh = Kb + (size_t)bh * TSEQ * DHEAD;
  const unsigned short* Vh = VTb + (size_t)bh * DHEAD * TSEQ;
  unsigned short* P = &Psm[wid][0];
  int swzl = (l15 & 7) << 4;

  int krow = tid >> 4;
  int kcol = (((tid & 15) << 4) ^ ((krow & 7) << 4)) >> 1;
  int vrow = tid >> 3;
  int vcol = (((tid & 7) << 4) ^ ((vrow & 7) << 4)) >> 1;
  int ldsl = tid * 8;

  int ck[4];
  #pragma unroll
  for (int kk = 0; kk < 4; ++kk) ck[kk] = ((kk * 64 + l16 * 16) ^ swzl) >> 1;

  bf16x8 qf[2][4];
  f32x4 accO[2][8];
  float mrow[2][4], lrow[2][4];   // lrow = PER-LANE partial row sum

  int qbase = hi * 128 + wid * 32;
  #pragma unroll
  for (int m = 0; m < 2; ++m) {
    #pragma unroll
    for (int n = 0; n < 8; ++n) accO[m][n] = (f32x4)0.f;
    #pragma unroll
    for (int r = 0; r < 4; ++r) { mrow[m][r] = -1e30f; lrow[m][r] = 0.f; }
    #pragma unroll
    for (int kk = 0; kk < 4; ++kk)
      qf[m][kk] = *(const bf16x8*)&Qb[((size_t)bh * TSEQ + qbase + m * 16 + l15) * DHEAD
                                      + kk * 32 + l16 * 8];
  }

  int nt0 = 2 * hi + 2;
  int ntt = nt0 + 2 * lo + 2;

  {
    const unsigned short* kg = Kh + krow * DHEAD + kcol;
    const unsigned short* vg = Vh + (size_t)vrow * TSEQ + vcol;
    #pragma unroll
    for (int ps = 0; ps < 4; ++ps) {
      gl_lds16(kg + ps * 16 * DHEAD, &Ksm[0][ldsl + ps * 2048]);
      gl_lds16(vg + (size_t)ps * 32 * TSEQ, &Vsm[0][ldsl + ps * 2048]);
    }
  }
  __syncthreads();

  for (int it = 0; it < ntt; ++it) {
    int buf = it & 1;
    int kv0 = ((it >= nt0) ? (it - nt0) : it) * 64;

    if (it + 1 < ntt) {
      int n2 = it + 1;
      int kv2 = ((n2 >= nt0) ? (n2 - nt0) : n2) * 64;
      const unsigned short* kg = Kh + (size_t)(kv2 + krow) * DHEAD + kcol;
      const unsigned short* vg = Vh + (size_t)vrow * TSEQ + kv2 + vcol;
      #pragma unroll
      for (int ps = 0; ps < 4; ++ps) {
        gl_lds16(kg + ps * 16 * DHEAD, &Ksm[buf ^ 1][ldsl + ps * 2048]);
        gl_lds16(vg + (size_t)ps * 32 * TSEQ, &Vsm[buf ^ 1][ldsl + ps * 2048]);
      }
    }

    if (kv0 <= qbase + 31) {
      const unsigned short* Kt = Ksm[buf];
      const unsigned short* Vt = Vsm[buf];

      f32x4 S[2][4] = {};
      #pragma unroll
      for (int n = 0; n < 4; ++n) {
        bf16x8 kf[4];
        #pragma unroll
        for (int kk = 0; kk < 4; ++kk)
          kf[kk] = *(const bf16x8*)&Kt[(n * 16 + l15) * DHEAD + ck[kk]];
        #pragma unroll
        for (int m = 0; m < 2; ++m)
          #pragma unroll
          for (int kk = 0; kk < 4; ++kk)
            S[m][n] = __builtin_amdgcn_mfma_f32_16x16x32_bf16(qf[m][kk], kf[kk], S[m][n], 0, 0, 0);
      }

      // ---- pass 1: mask (diagonal tile only) + per-lane LOCAL max ----
      bool masked = (kv0 + 63 > qbase);    // wave-uniform
      float lmax[2][4];
      float grow = -1e30f;
      #pragma unroll
      for (int m = 0; m < 2; ++m) {
        #pragma unroll
        for (int r = 0; r < 4; ++r) {
          if (masked) {
            int qg = qbase + m * 16 + l16 * 4 + r;
            if (kv0 + l15      > qg) S[m][0][r] = -1e30f;
            if (kv0 + 16 + l15 > qg) S[m][1][r] = -1e30f;
            if (kv0 + 32 + l15 > qg) S[m][2][r] = -1e30f;
            if (kv0 + 48 + l15 > qg) S[m][3][r] = -1e30f;
          }
          float v = fmaxf(fmaxf(S[m][0][r], S[m][1][r]), fmaxf(S[m][2][r], S[m][3][r]));
          lmax[m][r] = v;
          grow = fmaxf(grow, v - mrow[m][r]);
        }
      }

      // ---- defer-max: full reduce + rescale only when some LANE grew >8 ----
      if (__any(grow > 8.f)) {
        #pragma unroll
        for (int m = 0; m < 2; ++m)
          #pragma unroll
          for (int r = 0; r < 4; ++r) {
            float v = lmax[m][r];
            #pragma unroll
            for (int off = 1; off < 16; off <<= 1) v = fmaxf(v, __shfl_xor(v, off));
            float mnew = fmaxf(mrow[m][r], v);
            float alpha = exp2f(mrow[m][r] - mnew);
            mrow[m][r] = mnew;
            lrow[m][r] *= alpha;
            #pragma unroll
            for (int n = 0; n < 8; ++n) accO[m][n][r] *= alpha;
          }
      }

      // ---- pass 2: P = exp2(S - m), per-lane partial sums, P writes ----
      #pragma unroll
      for (int m = 0; m < 2; ++m) {
        #pragma unroll
        for (int r = 0; r < 4; ++r) {
          float mr = mrow[m][r];
          float p0 = exp2f(S[m][0][r] - mr), p1 = exp2f(S[m][1][r] - mr);
          float p2 = exp2f(S[m][2][r] - mr), p3 = exp2f(S[m][3][r] - mr);
          lrow[m][r] += (p0 + p1) + (p2 + p3);   // partial; reduced at flush
          int qr = m * 16 + l16 * 4 + r;
          int ws = (qr & 7) << 4;
          P[qr * 64 + ((((l15 << 1))      ^ ws) >> 1)] = f2bf_t(p0);
          P[qr * 64 + (((32 + (l15 << 1)) ^ ws) >> 1)] = f2bf_t(p1);
          P[qr * 64 + (((64 + (l15 << 1)) ^ ws) >> 1)] = f2bf_t(p2);
          P[qr * 64 + (((96 + (l15 << 1)) ^ ws) >> 1)] = f2bf_t(p3);
        }
      }

      bf16x8 pf[2][2];
      #pragma unroll
      for (int m = 0; m < 2; ++m)
        #pragma unroll
        for (int kk = 0; kk < 2; ++kk)
          pf[m][kk] = *(const bf16x8*)&P[(m * 16 + l15) * 64 + ck[kk]];
      #pragma unroll
      for (int n = 0; n < 8; ++n) {
        bf16x8 vf[2];
        #pragma unroll
        for (int kk = 0; kk < 2; ++kk)
          vf[kk] = *(const bf16x8*)&Vt[(n * 16 + l15) * 64 + ck[kk]];
        #pragma unroll
        for (int m = 0; m < 2; ++m)
          #pragma unroll
          for (int kk = 0; kk < 2; ++kk)
            accO[m][n] = __builtin_amdgcn_mfma_f32_16x16x32_bf16(pf[m][kk], vf[kk], accO[m][n], 0, 0, 0);
      }
    }

    if (it == nt0 - 1) {
      int b = bh >> 4, h = bh & 15;
      #pragma unroll
      for (int m = 0; m < 2; ++m)
        #pragma unroll
        for (int r = 0; r < 4; ++r) {
          float ls = lrow[m][r];
          #pragma unroll
          for (int off = 1; off < 16; off <<= 1) ls += __shfl_xor(ls, off);
          float inv = 1.0f / ls;
          int t = qbase + m * 16 + l16 * 4 + r;
          size_t base = ((size_t)b * TSEQ + t) * D_MODEL + h * DHEAD;
          #pragma unroll
          for (int n = 0; n < 8; ++n)
            ctx[base + n * 16 + l15] = f2bf(accO[m][n][r] * inv);
        }
      qbase = lo * 128 + wid * 32;
      #pragma unroll
      for (int m = 0; m < 2; ++m) {
        #pragma unroll
        for (int n = 0; n < 8; ++n) accO[m][n] = (f32x4)0.f;
        #pragma unroll
        for (int r = 0; r < 4; ++r) { mrow[m][r] = -1e30f; lrow[m][r] = 0.f; }
        #pragma unroll
        for (int kk = 0; kk < 4; ++kk)
          qf[m][kk] = *(const bf16x8*)&Qb[((size_t)bh * TSEQ + qbase + m * 16 + l15) * DHEAD
                                          + kk * 32 + l16 * 8];
      }
    }

    __syncthreads();
  }

  {
    int b = bh >> 4, h = bh & 15;
    #pragma unroll
    for (int m = 0; m < 2; ++m)
      #pragma unroll
      for (int r = 0; r < 4; ++r) {
        float ls = lrow[m][r];
        #pragma unroll
        for (int off = 1; off < 16; off <<= 1) ls += __shfl_xor(ls, off);
        float inv = 1.0f / ls;
        int t = qbase + m * 16 + l16 * 4 + r;
        size_t base = ((size_t)b * TSEQ + t) * D_MODEL + h * DHEAD;
        #pragma unroll
        for (int n = 0; n < 8; ++n)
          ctx[base + n * 16 + l15] = f2bf(accO[m][n][r] * inv);
      }
  }
}

extern "C" void kernel_launch(void* const* d_in, const int* in_sizes, int n_in,
                              void* d_out, int out_size, void* d_ws, size_t ws_size,
                              hipStream_t stream)
{
  const float* x     = (const float*)d_in[0];
  const float* w_qkv = (const float*)d_in[1];
  const float* b_qkv = (const float*)d_in[2];
  const float* w_out = (const float*)d_in[3];
  const float* b_out = (const float*)d_in[4];
  float* out = (float*)d_out;

  unsigned short* xb    = (unsigned short*)d_ws;               // [8192][2048]; reused as ctx
  unsigned short* wqkvT = xb    + (size_t)MROWS * D_MODEL;     // [6144][2048]
  unsigned short* woutT = wqkvT + (size_t)NQKV * D_MODEL;      // [2048][2048]
  unsigned short* Qb    = woutT + (size_t)D_MODEL * D_MODEL;   // [64][2048][128]
  unsigned short* Kb    = Qb    + (size_t)BH * TSEQ * DHEAD;
  unsigned short* VTb   = Kb    + (size_t)BH * TSEQ * DHEAD;   // [64][128][2048]
  float2* tab = (float2*)(VTb + (size_t)BH * TSEQ * DHEAD);    // [2048][64]

  cvt_bf16<<<MROWS * D_MODEL / 2048, 256, 0, stream>>>(x, xb, MROWS * D_MODEL);
  transw<<<dim3(NQKV / 32, D_MODEL / 32), 256, 0, stream>>>(w_qkv, wqkvT, D_MODEL, NQKV);
  transw<<<dim3(D_MODEL / 32, D_MODEL / 32), 256, 0, stream>>>(w_out, woutT, D_MODEL, D_MODEL);
  rope_table<<<TSEQ, 64, 0, stream>>>(tab);
  gemm_bt<0><<<dim3(NQKV / 256, MROWS / 256), 512, 0, stream>>>(
      xb, wqkvT, b_qkv, MROWS, NQKV, D_MODEL, Qb, Kb, VTb, nullptr, tab);
  attn_fwd<<<dim3(512), 256, 0, stream>>>(Qb, Kb, VTb, xb);
  gemm_bt<1><<<dim3(D_MODEL / 256, MROWS / 256), 512, 0, stream>>>(
      xb, woutT, b_out, MROWS, D_MODEL, D_MODEL, nullptr, nullptr, nullptr, out, nullptr);
}